// Round 11
// baseline (428.555 us; speedup 1.0000x reference)
//
#include <hip/hip_runtime.h>

// out[b,s,j] = sum_k x[b,s,k] * w_concat[inv_perm[j], k] + bias[j]
// INT8 path: weights exact in i8; x per-token quantized (sx = absmax/127).
// Round 10: OCCUPANCY structure. BM=256 x BN=128, BK=64, 8 waves of 64x64,
// acc=64 regs/wave, LDS 48KB -> TWO blocks per CU (4 waves/SIMD): block A's
// barrier/LDS phases overlap block B's MFMAs (m114 mechanism). Simple
// compiler-scheduled K-loop; additive 16B-chunk rotation swizzle (2-way max).

#define M_TOK 16384
#define N_O   4096
#define K_IN  4096
#define N8F   2048
#define NT    (K_IN / 64)    // 64 K-tiles of BK=64 i8 (64 B/row)

typedef __attribute__((ext_vector_type(4))) int i32x4;

__device__ __forceinline__ void gl_lds16(const void* g, void* l) {
  __builtin_amdgcn_global_load_lds(
      (const __attribute__((address_space(1))) unsigned int*)g,
      (__attribute__((address_space(3))) unsigned int*)l, 16, 0, 0);
}

__device__ __forceinline__ int clampq(float f) {
  int q = (int)rintf(f);
  return q > 127 ? 127 : (q < -127 ? -127 : q);
}

// ---- fused prep: blocks [0,N_O) pack weights to i8; blocks [N_O, N_O+M_TOK)
// ---- quantize one token each (absmax -> sx, xq). Row-major i8, 4096 B rows.
__global__ void prep_kernel(const float* __restrict__ x,
                            const int4* __restrict__ q8, const float* __restrict__ s8,
                            const int4* __restrict__ q4, const float* __restrict__ s4,
                            const int* __restrict__ inv,
                            char* __restrict__ Wq, float* __restrict__ scale,
                            float* __restrict__ sx, char* __restrict__ xq) {
  __shared__ float red[4];
  const int t = threadIdx.x;
  if (blockIdx.x < N_O) {
    const int j = blockIdx.x;
    const int c = inv[j];
    const int4* src; float s;
    if (c < N8F) { src = q8 + (size_t)c * (K_IN / 4);         s = s8[c]; }
    else         { src = q4 + (size_t)(c - N8F) * (K_IN / 4); s = s4[c - N8F]; }
    if (t == 0) scale[j] = s;
    unsigned dw[4];
#pragma unroll
    for (int i = 0; i < 4; ++i) {
      int4 v = src[t * 4 + i];
      dw[i] = (v.x & 255) | ((v.y & 255) << 8) | ((v.z & 255) << 16)
            | ((unsigned)(v.w & 255) << 24);
    }
    *(uint4*)(Wq + (size_t)j * K_IN + t * 16) = make_uint4(dw[0], dw[1], dw[2], dw[3]);
  } else {
    const int T = blockIdx.x - N_O;
    const float4* xr = (const float4*)(x + (size_t)T * K_IN);
    float4 v[4];
    float m = 0.f;
#pragma unroll
    for (int i = 0; i < 4; ++i) {
      v[i] = xr[t * 4 + i];
      m = fmaxf(m, fmaxf(fmaxf(fabsf(v[i].x), fabsf(v[i].y)),
                         fmaxf(fabsf(v[i].z), fabsf(v[i].w))));
    }
#pragma unroll
    for (int o = 32; o; o >>= 1) m = fmaxf(m, __shfl_xor(m, o));
    if ((t & 63) == 0) red[t >> 6] = m;
    __syncthreads();
    m = fmaxf(fmaxf(red[0], red[1]), fmaxf(red[2], red[3]));
    const float rq = m > 0.f ? 127.f / m : 0.f;
    if (t == 0) sx[T] = m * (1.f / 127.f);
    unsigned dw[4];
#pragma unroll
    for (int i = 0; i < 4; ++i) {
      int a0 = clampq(v[i].x * rq), a1 = clampq(v[i].y * rq);
      int a2 = clampq(v[i].z * rq), a3 = clampq(v[i].w * rq);
      dw[i] = (a0 & 255) | ((a1 & 255) << 8) | ((a2 & 255) << 16)
            | ((unsigned)(a3 & 255) << 24);
    }
    *(uint4*)(xq + (size_t)T * K_IN + t * 16) = make_uint4(dw[0], dw[1], dw[2], dw[3]);
  }
}

// ================= 256x128 i8 GEMM, BK=64, 2 blocks/CU =================
// LDS (48 KiB): buf*24576 + { A: 16 KiB (256 rows x 64B) | B at 16384: 8 KiB }
// swizzle: phys_chunk = (logical_chunk + (row>>1)) & 3   (16B chunks in 64B row)
__global__ __launch_bounds__(512, 4)
void gemm_i8(const char* __restrict__ xq, const char* __restrict__ Wq,
             const float* __restrict__ sx, const float* __restrict__ scale,
             const float* __restrict__ bias, float* __restrict__ out) {
  __shared__ __align__(16) char sm[49152];
  const int t = threadIdx.x;
  const int w = t >> 6, l = t & 63;
  const int wr = w >> 1, wc = w & 1;          // 4M x 2N waves, 64x64 each
  // bijective XCD remap (2048 blocks, 2048%8==0): xcd chunk = 8bm x 32bn
  const int wg = blockIdx.x;
  const int xcd = wg & 7, idx = wg >> 3;      // idx in [0,256)
  const int bm = (xcd << 3) | (idx >> 5);     // [0,64)
  const int bn = idx & 31;                    // [0,32)
  const int row0 = bm * 256, col0 = bn * 128;

  // --- staging: per-lane pre-rotated global source (rule #21) ---
  // gl_lds dest linear: lane l -> row l>>2, phys chunk l&3 within a 16-row slice.
  // phys chunk (l&3) at abs row r holds logical chunk ((l&3) - (r>>1))&3;
  // for 16-aligned slice bases, (r>>1)&3 == (l>>3)&3  (per-lane constant).
  const int srow = l >> 2;
  const int schunk = (((l & 3) - ((l >> 3) & 3)) & 3) * 16;
  const char* aGw = xq + (size_t)(row0 + w * 32 + srow) * K_IN + schunk;
  const char* bGw = Wq + (size_t)(col0 + w * 16 + srow) * K_IN + schunk;

  auto stage = [&](int buf, int kt) {
    const int o = kt << 6;
    char* aD = sm + buf * 24576 + w * 2048;
    char* bD = sm + buf * 24576 + 16384 + w * 1024;
    gl_lds16(aGw + o, aD);                      // A rows w*32 .. +16
    gl_lds16(aGw + 16 * K_IN + o, aD + 1024);   // A rows w*32+16 .. +32
    gl_lds16(bGw + o, bD);                      // B rows w*16 .. +16
  };

  // --- fragment-read per-lane offsets (rotation swizzle) ---
  // frag row r = base16 + (l&15), chunk c = l>>4; phys chunk = (c + ((l&15)>>1))&3
  const int rfoff = (l & 15) * 64 + ((((l >> 4) & 3) + (((l & 15) >> 1) & 3)) & 3) * 16;
  const char* rA0 = sm + rfoff;                 // + buf*24576 + wr*4096 + m*1024
  const char* rB0 = sm + 16384 + rfoff;         // + buf*24576 + wc*4096 + n*1024

  i32x4 acc[4][4];
#pragma unroll
  for (int m = 0; m < 4; ++m)
#pragma unroll
    for (int n = 0; n < 4; ++n) acc[m][n] = (i32x4){0, 0, 0, 0};

  // --- prologue ---
  stage(0, 0);
  __syncthreads();

  for (int kt2 = 0; kt2 < NT; kt2 += 2) {
#pragma unroll
    for (int half = 0; half < 2; ++half) {
      const int kt = kt2 + half;
      const int cur = half;
      if (kt + 1 < NT) stage(cur ^ 1, kt + 1);

      const char* rA = rA0 + cur * 24576 + wr * 4096;
      const char* rB = rB0 + cur * 24576 + wc * 4096;
      i32x4 a[4], b[4];
#pragma unroll
      for (int n = 0; n < 4; ++n) b[n] = *(const i32x4*)(rB + n * 1024);
#pragma unroll
      for (int m = 0; m < 4; ++m) a[m] = *(const i32x4*)(rA + m * 1024);
#pragma unroll
      for (int m = 0; m < 4; ++m)
#pragma unroll
        for (int n = 0; n < 4; ++n)
          acc[m][n] = __builtin_amdgcn_mfma_i32_16x16x64_i8(a[m], b[n],
                                                            acc[m][n], 0, 0, 0);
      // one publish per K-tile: drains my ds_reads (cur overwritten next tile)
      // and my gl_lds writes (buf^1 consumed next tile), then barrier.
      __syncthreads();
    }
  }

  // ---- epilogue: C/D col=lane&15, row=(lane>>4)*4+i ; out = acc*sx[r]*sc + bias
  const int orow0 = row0 + wr * 64 + ((l >> 4) << 2);
  const int ocol0 = col0 + wc * 64 + (l & 15);
#pragma unroll
  for (int n = 0; n < 4; ++n) {
    const int col = ocol0 + n * 16;
    const float sc = scale[col];
    const float bi = bias[col];
#pragma unroll
    for (int m = 0; m < 4; ++m) {
      const int r = orow0 + m * 16;
      const float4 sxv = *(const float4*)(sx + r);
      out[(size_t)(r + 0) * N_O + col] = (float)acc[m][n][0] * (sxv.x * sc) + bi;
      out[(size_t)(r + 1) * N_O + col] = (float)acc[m][n][1] * (sxv.y * sc) + bi;
      out[(size_t)(r + 2) * N_O + col] = (float)acc[m][n][2] * (sxv.z * sc) + bi;
      out[(size_t)(r + 3) * N_O + col] = (float)acc[m][n][3] * (sxv.w * sc) + bi;
    }
  }
}

extern "C" void kernel_launch(void* const* d_in, const int* in_sizes, int n_in,
                              void* d_out, int out_size, void* d_ws, size_t ws_size,
                              hipStream_t stream) {
  const float* x    = (const float*)d_in[0];
  const int*   q8   = (const int*)d_in[1];
  const float* s8   = (const float*)d_in[2];
  const int*   q4   = (const int*)d_in[3];
  const float* s4   = (const float*)d_in[4];
  const int*   inv  = (const int*)d_in[5];
  const float* bias = (const float*)d_in[6];
  float* out = (float*)d_out;

  // ws layout: Wq (16 MiB) | scale (16 KiB) | sx (64 KiB) | xq (64 MiB)
  char* ws = (char*)d_ws;
  char*  Wq    = ws;
  float* scale = (float*)(ws + (size_t)N_O * K_IN);
  float* sx    = (float*)(ws + (size_t)N_O * K_IN + 65536);
  char*  xq    = ws + (size_t)N_O * K_IN + 65536 + 65536;

  prep_kernel<<<N_O + M_TOK, 256, 0, stream>>>(x, (const int4*)q8, s8,
                                               (const int4*)q4, s4, inv,
                                               Wq, scale, sx, xq);
  gemm_i8<<<(M_TOK / 256) * (N_O / 128), 512, 0, stream>>>(xq, Wq, sx, scale,
                                                           bias, out);
}